// Round 8
// baseline (467.552 us; speedup 1.0000x reference)
//
#include <hip/hip_runtime.h>

// GAT layer, N=8192, H=4, d=128.
// softmax_j(src_i + tgt_j) masked == adj-normalized w_j = exp(tgt_j); src cancels:
//   out[i,d] = 0.25 * sum_h ( (adj @ (w_h*ht_h))[i,d] / (adj @ w_h)[i] )
// Pipeline:
//   k0: Wt = W^T
//   k1: HT = leakyrelu(h @ W) bf16 MFMA        [8192 x 512]
//   k2: build Yt in FRAGMENT-MAJOR layout: tile (R=row/16, T=k/32) is a
//       1 KB block [q=(k%32)/8][r=row%16][e=k%8] bf16. Rows 0..511 =
//       w[g,j]*ht[j,g,d]; 512..515 = w[g,j]; 516..527 = 0. 33 R x 256 T.
//   k3: adj_gemm v8: BM=128, BN=512(+den), 8 waves, grid (4,64) kh->XCD
//       pinned (each XCD L2 holds its 2.1 MB Yt quarter). B loaded DIRECT
//       global->reg: one fully-coalesced 1KB dwordx4 per fragment
//       (addr = tile_base + lane*8). No B-LDS, no GLD16, no vmcnt drain.
//       A (adj) nt-loads -> swizzled LDS dbuf, lgkm-only barrier per step.
//   k4: out = 0.25 * sum_g (sum_kh C_kh)[i,512g+d] / (sum_kh S_kh)[g,i]
// ws ~85 MB: Wt 0.5M | HT 8M | Yt 8.65M | C 64M | S 0.5M

typedef unsigned short u16;
typedef unsigned int u32;
using bf16x8 = __attribute__((ext_vector_type(8))) short;
using f32x4  = __attribute__((ext_vector_type(4))) float;
using i32x4  = __attribute__((ext_vector_type(4))) int;

__device__ __forceinline__ u16 f2bf(float f) {
  u32 u = __float_as_uint(f);
  return (u16)((u + 0x7FFFu + ((u >> 16) & 1u)) >> 16);  // RNE
}
__device__ __forceinline__ float bf2f(u16 u) {
  return __uint_as_float(((u32)u) << 16);
}

// ---------------- k0: transpose W [256][512] -> Wt [512][256] ----------------
__global__ void transpose_w(const float* __restrict__ W, float* __restrict__ Wt) {
  __shared__ float tile[32][33];
  int cb = blockIdx.x * 32, kb = blockIdx.y * 32;
  int tc = threadIdx.x & 31, tr = threadIdx.x >> 5;
  for (int p = 0; p < 32; p += 8)
    tile[tr + p][tc] = W[(size_t)(kb + tr + p) * 512 + cb + tc];
  __syncthreads();
  for (int p = 0; p < 32; p += 8)
    Wt[(size_t)(cb + tr + p) * 256 + kb + tc] = tile[tc][tr + p];
}

// ---------------- k1: HT = leaky(h @ W), bf16 out [8192][512] ----------------
__global__ void ht_gemm(const float* __restrict__ h, const float* __restrict__ Wt,
                        u16* __restrict__ HT) {
  __shared__ __align__(16) u16 Abuf[128 * 40];
  __shared__ __align__(16) u16 Bbuf[128 * 40];
  int tid = threadIdx.x;
  int cb = blockIdx.x, rb = blockIdx.y;
  int r0 = rb * 128, c0 = cb * 128;
  int lane = tid & 63, wv = tid >> 6;
  int wr = wv >> 1, wc = wv & 1;
  int mrow = lane & 15, q = lane >> 4;
  int ch = tid & 7, m0 = tid >> 3;

  f32x4 acc[4][4];
#pragma unroll
  for (int i = 0; i < 4; i++)
#pragma unroll
    for (int j = 0; j < 4; j++) acc[i][j] = f32x4{0.f, 0.f, 0.f, 0.f};

  for (int kt = 0; kt < 256; kt += 32) {
    __syncthreads();
#pragma unroll
    for (int mp = 0; mp < 128; mp += 32) {
      int m = m0 + mp;
      float4 v = *(const float4*)(&h[(size_t)(r0 + m) * 256 + kt + ch * 4]);
      uint2 p;
      p.x = (u32)f2bf(v.x) | ((u32)f2bf(v.y) << 16);
      p.y = (u32)f2bf(v.z) | ((u32)f2bf(v.w) << 16);
      *(uint2*)(&Abuf[m * 40 + ch * 4]) = p;
      float4 u = *(const float4*)(&Wt[(size_t)(c0 + m) * 256 + kt + ch * 4]);
      uint2 r;
      r.x = (u32)f2bf(u.x) | ((u32)f2bf(u.y) << 16);
      r.y = (u32)f2bf(u.z) | ((u32)f2bf(u.w) << 16);
      *(uint2*)(&Bbuf[m * 40 + ch * 4]) = r;
    }
    __syncthreads();
    bf16x8 af[4], bfv[4];
#pragma unroll
    for (int i = 0; i < 4; i++)
      af[i] = *(const bf16x8*)(&Abuf[(wr * 64 + i * 16 + mrow) * 40 + q * 8]);
#pragma unroll
    for (int j = 0; j < 4; j++)
      bfv[j] = *(const bf16x8*)(&Bbuf[(wc * 64 + j * 16 + mrow) * 40 + q * 8]);
#pragma unroll
    for (int i = 0; i < 4; i++)
#pragma unroll
      for (int j = 0; j < 4; j++)
        acc[i][j] = __builtin_amdgcn_mfma_f32_16x16x32_bf16(af[i], bfv[j], acc[i][j], 0, 0, 0);
  }
#pragma unroll
  for (int i = 0; i < 4; i++)
#pragma unroll
    for (int j = 0; j < 4; j++)
#pragma unroll
      for (int r = 0; r < 4; r++) {
        int gi = r0 + wr * 64 + i * 16 + q * 4 + r;
        int gc = c0 + wc * 64 + j * 16 + mrow;
        float v = acc[i][j][r];
        v = v >= 0.f ? v : 0.1f * v;
        HT[(size_t)gi * 512 + gc] = f2bf(v);
      }
}

// ---------------- k2: build Yt (fragment-major) ----------------
// Yt u16 index for (row c, graph-node j):
//   ((c/16)*256 + j/32)*512 + ((j%32)/8)*128 + (c%16)*8 + (j%8)
__global__ void build_yt(const u16* __restrict__ HT, const float* __restrict__ a,
                         u16* __restrict__ Yt) {
  __shared__ u16 sht[32][528];
  __shared__ float swv[32 * 4];
  __shared__ float sa[512];
  int t = threadIdx.x;
  int j0 = blockIdx.x * 32;
  for (int i = t; i < 512; i += 256) {
    int g = i >> 7, d = i & 127;
    sa[i] = a[g * 256 + 128 + d];
  }
#pragma unroll
  for (int p = 0; p < 8; ++p) {
    int el = t + 256 * p;                 // 2048 uint4 slots: 32 rows x 64
    int row = el >> 6, col8 = el & 63;
    *(uint4*)(&sht[row][col8 * 8]) = *(const uint4*)(&HT[(size_t)(j0 + row) * 512 + col8 * 8]);
  }
  __syncthreads();
  if (t < 128) {
    int jl = t >> 2, g = t & 3;
    float acc = 0.f;
#pragma unroll
    for (int d8 = 0; d8 < 16; ++d8) {
      bf16x8 v = *(const bf16x8*)(&sht[jl][g * 128 + d8 * 8]);
#pragma unroll
      for (int u = 0; u < 8; ++u)
        acc += bf2f((u16)v[u]) * sa[g * 128 + d8 * 8 + u];
    }
    swv[jl * 4 + g] = __expf(acc);
  }
  __syncthreads();
  int oj = (t & 3) * 8, oc = t >> 2;      // oj = q*8 (j-octet), oc among 64 c
  size_t T = j0 >> 5;
  for (int pass = 0; pass < 9; ++pass) {
    int c = pass * 64 + oc;
    if (c >= 528) break;
    u32 pk[4] = {0u, 0u, 0u, 0u};
    if (c < 512) {
      int g = c >> 7;
#pragma unroll
      for (int u = 0; u < 4; ++u) {
        int j = oj + 2 * u;
        float v0 = bf2f(sht[j][c]) * swv[j * 4 + g];
        float v1 = bf2f(sht[j + 1][c]) * swv[(j + 1) * 4 + g];
        pk[u] = (u32)f2bf(v0) | ((u32)f2bf(v1) << 16);
      }
    } else if (c < 516) {
      int g = c - 512;
#pragma unroll
      for (int u = 0; u < 4; ++u) {
        int j = oj + 2 * u;
        float v0 = swv[j * 4 + g];
        float v1 = swv[(j + 1) * 4 + g];
        pk[u] = (u32)f2bf(v0) | ((u32)f2bf(v1) << 16);
      }
    }
    size_t dst = ((size_t)(c >> 4) * 256 + T) * 512 + (size_t)(oj >> 3) * 128 + (c & 15) * 8;
    *(uint4*)(&Yt[dst]) = make_uint4(pk[0], pk[1], pk[2], pk[3]);
  }
}

// ---------------- k3: adj GEMM v8 -- B direct-to-reg, coalesced ------------
// grid (4, 64) = (kh, rb): XCD = linear%8 in {kh, kh+4} -> each XCD's L2
// holds ONE 2.1 MB Yt quarter. 512 threads = 8 waves (2 wr x 4 wc).
// B fragment (R = wc*8+j, T) = 1 KB contiguous block; lane addr = base+lane*8
// -> one coalesced global_load_dwordx4 per fragment, L2-hit. No B LDS.
// A: nt global -> regs -> swizzled LDS dbuf; lgkm-only barrier per step.
__global__ __launch_bounds__(512) void adj_gemm(const int* __restrict__ adj,
                                                const u16* __restrict__ Yt,
                                                float* __restrict__ C,
                                                float* __restrict__ S) {
  __shared__ __align__(16) u16 Abuf[2][128 * 32];   // 16 KB total
  int tid = threadIdx.x;
  int rb = blockIdx.y, kh = blockIdx.x;             // kh fastest -> XCD pin
  int r0 = rb * 128, k0 = kh * 2048;
  int lane = tid & 63, wv = tid >> 6;
  int wr = wv >> 2, wc = wv & 3;
  int mrow = lane & 15, q = lane >> 4;
  int qs = q ^ ((mrow >> 1) & 3);                   // swizzled A read slot
  int am = tid >> 2, aq = tid & 3;                  // A staging row / slot
  int asw = am * 32 + ((aq ^ ((am >> 1) & 3)) * 8); // swizzled A store off
  const int* abase = &adj[(size_t)(r0 + am) * 8192 + k0 + aq * 8];
  bool do_den = (wc == 0);
  // B fragment bases: frag (j, t) at ybase + (j*256 + t)*512 u16
  const u16* ybase = Yt + ((size_t)(wc * 8) * 256 + (k0 >> 5)) * 512 + (size_t)lane * 8;
  const u16* dbase = Yt + ((size_t)32 * 256 + (k0 >> 5)) * 512 + (size_t)lane * 8;

  f32x4 acc[4][8];
#pragma unroll
  for (int i = 0; i < 4; i++)
#pragma unroll
    for (int j = 0; j < 8; j++) acc[i][j] = f32x4{0.f, 0.f, 0.f, 0.f};
  f32x4 accD[4];
#pragma unroll
  for (int i = 0; i < 4; i++) accD[i] = f32x4{0.f, 0.f, 0.f, 0.f};

#define LOADA(V0, V1, TT)                                              \
  {                                                                    \
    const int* ap = abase + (size_t)(TT) * 32;                         \
    V0 = __builtin_nontemporal_load((const i32x4*)(ap));               \
    V1 = __builtin_nontemporal_load((const i32x4*)(ap + 4));           \
  }
#define PACKA(DST, V0, V1)                                             \
  {                                                                    \
    uint4 pk;                                                          \
    pk.x = 16256u * ((u32)V0[0] | ((u32)V0[1] << 16));                 \
    pk.y = 16256u * ((u32)V0[2] | ((u32)V0[3] << 16));                 \
    pk.z = 16256u * ((u32)V1[0] | ((u32)V1[1] << 16));                 \
    pk.w = 16256u * ((u32)V1[2] | ((u32)V1[3] << 16));                 \
    *(uint4*)((DST) + asw) = pk;                                       \
  }

  // ---- prologue: stage A tile 0 into buffer 0 ----
  {
    i32x4 a0, a1;
    LOADA(a0, a1, 0);
    PACKA(&Abuf[0][0], a0, a1);
  }
  asm volatile("s_waitcnt lgkmcnt(0)" ::: "memory");
  __builtin_amdgcn_s_barrier();

  for (int t = 0; t < 64; ++t) {
    // ---- B fragments for this step: coalesced 1KB loads (L2-hot) ----
    bf16x8 bfv[8];
#pragma unroll
    for (int j = 0; j < 8; j++)
      bfv[j] = *(const bf16x8*)(ybase + ((size_t)j * 256 + t) * 512);
    bf16x8 bd;
    if (do_den) bd = *(const bf16x8*)(dbase + (size_t)t * 512);
    // ---- A prefetch (t+1); lands under the MFMAs ----
    i32x4 v0, v1;
    if (t < 63) LOADA(v0, v1, t + 1);
    // ---- A fragments from LDS ----
    bf16x8 af[4];
    const u16* Ab = &Abuf[t & 1][0];
#pragma unroll
    for (int i = 0; i < 4; i++)
      af[i] = *(const bf16x8*)(&Ab[(wr * 64 + i * 16 + mrow) * 32 + qs * 8]);
    // ---- MFMAs (bfv consumed in order -> counted vmcnt waits) ----
    __builtin_amdgcn_s_setprio(1);
#pragma unroll
    for (int j = 0; j < 8; j++)
#pragma unroll
      for (int i = 0; i < 4; i++)
        acc[i][j] = __builtin_amdgcn_mfma_f32_16x16x32_bf16(af[i], bfv[j], acc[i][j], 0, 0, 0);
    if (do_den) {
#pragma unroll
      for (int i = 0; i < 4; i++)
        accD[i] = __builtin_amdgcn_mfma_f32_16x16x32_bf16(af[i], bd, accD[i], 0, 0, 0);
    }
    __builtin_amdgcn_s_setprio(0);
    // ---- finish staging A(t+1) ----
    if (t < 63) PACKA(&Abuf[(t + 1) & 1][0], v0, v1);
    asm volatile("s_waitcnt lgkmcnt(0)" ::: "memory");
    __builtin_amdgcn_s_barrier();
  }
#undef LOADA
#undef PACKA

  float* Ck = C + (size_t)kh * 8192 * 512;
#pragma unroll
  for (int i = 0; i < 4; i++)
#pragma unroll
    for (int j = 0; j < 8; j++)
#pragma unroll
      for (int r = 0; r < 4; r++) {
        int gi = r0 + wr * 64 + i * 16 + q * 4 + r;
        int gc = wc * 128 + j * 16 + mrow;
        Ck[(size_t)gi * 512 + gc] = acc[i][j][r];
      }
  if (do_den && mrow < 4) {
    float* Sk = S + (size_t)kh * 4 * 8192;
#pragma unroll
    for (int i = 0; i < 4; i++)
#pragma unroll
      for (int r = 0; r < 4; r++) {
        int gi = r0 + wr * 64 + i * 16 + q * 4 + r;
        Sk[(size_t)mrow * 8192 + gi] = accD[i][r];
      }
  }
}

// ---------------- k4: combine K-split + heads ----------------
__global__ void finalize_gat(const float* __restrict__ C, const float* __restrict__ S,
                             float* __restrict__ out) {
  int idx = blockIdx.x * 256 + threadIdx.x;
  int i = idx >> 7, d = idx & 127;
  float s = 0.f;
#pragma unroll
  for (int g = 0; g < 4; ++g) {
    float num = 0.f, den = 0.f;
#pragma unroll
    for (int kh = 0; kh < 4; ++kh) {
      num += C[(size_t)kh * 8192 * 512 + (size_t)i * 512 + g * 128 + d];
      den += S[(size_t)kh * 4 * 8192 + (size_t)g * 8192 + i];
    }
    s += num / den;
  }
  out[idx] = 0.25f * s;
}

extern "C" void kernel_launch(void* const* d_in, const int* in_sizes, int n_in,
                              void* d_out, int out_size, void* d_ws, size_t ws_size,
                              hipStream_t stream) {
  const float* h   = (const float*)d_in[0];
  const int*   adj = (const int*)d_in[1];
  const float* W   = (const float*)d_in[2];
  const float* a   = (const float*)d_in[3];
  float* out = (float*)d_out;
  char* ws = (char*)d_ws;
  // ws: Wt 0.5M | HT 8M | Yt 8.65M | C 64M (4 x 16M) | S 0.5M  (~85 MB)
  float* Wt = (float*)(ws + 0);
  u16*   HT = (u16*)(ws + 524288);
  u16*   Yt = (u16*)(ws + 8912896);
  float* C  = (float*)(ws + 17563648);
  float* S  = (float*)(ws + 84672512);

  transpose_w<<<dim3(16, 8), 256, 0, stream>>>(W, Wt);
  ht_gemm<<<dim3(4, 64), 256, 0, stream>>>(h, Wt, HT);
  build_yt<<<dim3(256), 256, 0, stream>>>(HT, a, Yt);
  adj_gemm<<<dim3(4, 64), 512, 0, stream>>>(adj, Yt, C, S);
  finalize_gat<<<dim3(4096), 256, 0, stream>>>(C, S, out);
}